// Round 1
// 156.810 us; speedup vs baseline: 1.0279x; 1.0279x over previous
//
#include <hip/hip_runtime.h>
#include <hip/hip_bf16.h>
#include <math.h>

typedef _Float16 half8 __attribute__((ext_vector_type(8)));
typedef _Float16 half4_t __attribute__((ext_vector_type(4)));
typedef _Float16 half2_t __attribute__((ext_vector_type(2)));
typedef float floatx4 __attribute__((ext_vector_type(4)));
typedef float floatx2 __attribute__((ext_vector_type(2)));

#define MFMA16(a, b, c) __builtin_amdgcn_mfma_f32_16x16x32_f16(a, b, c, 0, 0, 0)
#define MASKVAL (-30000.0f)
// 1/sqrt(128) * log2(e), folded into wqt during prep
#define QSCALE 0.1275261529f

// ---------------------------------------------------------------------------
// Kernel 1: coalesced LDS-tiled weight transpose + fp32->fp16 convert.
// ---------------------------------------------------------------------------
__global__ __launch_bounds__(256) void wprep(
    const float* __restrict__ wq, const float* __restrict__ wk,
    const float* __restrict__ wv, const float* __restrict__ wo,
    _Float16* __restrict__ wqt, _Float16* __restrict__ wkt,
    _Float16* __restrict__ wvt, _Float16* __restrict__ wot) {
  __shared__ float T[32][36];
  int bx = blockIdx.x, tid = threadIdx.x;
  const float* src;
  _Float16* dst;
  int R, C, r0, c0;
  float sc = 1.0f;
  if (bx < 384) {
    int p = bx >> 7, t = bx & 127;
    src = (p == 0) ? wq : (p == 1) ? wk : wv;
    dst = (p == 0) ? wqt : (p == 1) ? wkt : wvt;
    if (p == 0) sc = QSCALE;
    R = 1024; C = 128;
    r0 = (t & 31) * 32; c0 = (t >> 5) * 32;
  } else {
    int t = bx - 384;
    src = wo; dst = wot;
    R = 128; C = 1024;
    r0 = (t & 3) * 32; c0 = (t >> 2) * 32;
  }
  {
    int row = tid >> 3, c4 = (tid & 7) * 4;
    float4 f = *(const float4*)&src[(size_t)(r0 + row) * C + c0 + c4];
    T[row][c4] = f.x; T[row][c4 + 1] = f.y; T[row][c4 + 2] = f.z; T[row][c4 + 3] = f.w;
  }
  __syncthreads();
  {
    int cc = tid >> 3, r4 = (tid & 7) * 4;
    half4_t h;
    h[0] = (_Float16)(T[r4 + 0][cc] * sc);
    h[1] = (_Float16)(T[r4 + 1][cc] * sc);
    h[2] = (_Float16)(T[r4 + 2][cc] * sc);
    h[3] = (_Float16)(T[r4 + 3][cc] * sc);
    *(half4_t*)&dst[(size_t)(c0 + cc) * R + r0 + r4] = h;
  }
}

// ---------------------------------------------------------------------------
// Kernel 2: QKV projection. 32-row x 128-col tiles, BK=128 (8 iterations),
// grid (256, 3) = 768 blocks = 3/CU. Register prefetch double-buffer.
// V written transposed Vt[(b*128+h)*2048+s] via LDS transpose so global
// stores are 32B-contiguous per thread (previous version scattered 2B
// stores across 64 cache lines per wave -> write amplification).
// ---------------------------------------------------------------------------
__global__ __launch_bounds__(256, 3) void qkv_gemm(
    const float* __restrict__ x, const _Float16* __restrict__ wqt,
    const _Float16* __restrict__ wkt, const _Float16* __restrict__ wvt,
    _Float16* __restrict__ Qh, _Float16* __restrict__ Kh,
    _Float16* __restrict__ Vt) {
  __shared__ _Float16 A_lds[32 * 136];
  __shared__ _Float16 B_lds[128 * 136];
  int tid = threadIdx.x;
  int w = tid >> 6, lane = tid & 63, quad = lane >> 4, l16 = lane & 15;
  int m0 = blockIdx.x * 32;
  int proj = blockIdx.y;
  const _Float16* wt = (proj == 0) ? wqt : (proj == 1) ? wkt : wvt;
  floatx4 zero = {0.f, 0.f, 0.f, 0.f};
  floatx4 acc[4];
#pragma unroll
  for (int t = 0; t < 4; t++) acc[t] = zero;

  int arow = tid >> 3, ac0 = (tid & 7) * 16;   // A: 32 rows, 16 floats/thr
  int brow = tid >> 1, bc0 = (tid & 1) * 64;   // B: 128 rows, 64 halfs/thr
  int mw = (w >> 1) * 16, nw = (w & 1) * 64;

  const float* asrc = x + (size_t)(m0 + arow) * 1024 + ac0;
  const _Float16* bsrc = wt + (size_t)brow * 1024 + bc0;

  float4 af[4];
  half8 bf[8];
#pragma unroll
  for (int i = 0; i < 4; i++) af[i] = ((const float4*)asrc)[i];
#pragma unroll
  for (int i = 0; i < 8; i++) bf[i] = ((const half8*)bsrc)[i];

  for (int k0 = 0; k0 < 1024; k0 += 128) {
    // dump staged registers to LDS (convert A fp32->fp16)
    {
      half8 h0, h1;
      h0[0] = (_Float16)af[0].x; h0[1] = (_Float16)af[0].y;
      h0[2] = (_Float16)af[0].z; h0[3] = (_Float16)af[0].w;
      h0[4] = (_Float16)af[1].x; h0[5] = (_Float16)af[1].y;
      h0[6] = (_Float16)af[1].z; h0[7] = (_Float16)af[1].w;
      h1[0] = (_Float16)af[2].x; h1[1] = (_Float16)af[2].y;
      h1[2] = (_Float16)af[2].z; h1[3] = (_Float16)af[2].w;
      h1[4] = (_Float16)af[3].x; h1[5] = (_Float16)af[3].y;
      h1[6] = (_Float16)af[3].z; h1[7] = (_Float16)af[3].w;
      *(half8*)&A_lds[arow * 136 + ac0] = h0;
      *(half8*)&A_lds[arow * 136 + ac0 + 8] = h1;
    }
#pragma unroll
    for (int i = 0; i < 8; i++)
      *(half8*)&B_lds[brow * 136 + bc0 + i * 8] = bf[i];
    __syncthreads();

    // prefetch next k-slice into registers (latency overlaps MFMA phase)
    if (k0 + 128 < 1024) {
      const float* a2 = asrc + k0 + 128;
      const _Float16* b2 = bsrc + k0 + 128;
#pragma unroll
      for (int i = 0; i < 4; i++) af[i] = ((const float4*)a2)[i];
#pragma unroll
      for (int i = 0; i < 8; i++) bf[i] = ((const half8*)b2)[i];
    }

    half8 a[4];
#pragma unroll
    for (int c = 0; c < 4; c++)
      a[c] = *(const half8*)&A_lds[(mw + l16) * 136 + c * 32 + quad * 8];
#pragma unroll
    for (int t = 0; t < 4; t++)
#pragma unroll
      for (int c = 0; c < 4; c++) {
        half8 b = *(const half8*)&B_lds[(nw + t * 16 + l16) * 136 + c * 32 + quad * 8];
        acc[t] = MFMA16(a[c], b, acc[t]);
      }
    __syncthreads();
  }
  if (proj < 2) {
#pragma unroll
    for (int t = 0; t < 4; t++)
#pragma unroll
      for (int r = 0; r < 4; r++) {
        int row = m0 + mw + quad * 4 + r;
        int col = nw + t * 16 + l16;
        _Float16 v = (_Float16)acc[t][r];
        if (proj == 0) Qh[(size_t)row * 128 + col] = v;
        else           Kh[(size_t)row * 128 + col] = v;
      }
  } else {
    // Transpose V tile [32 s x 128 d] through LDS; write coalesced.
    // (k-loop ended with __syncthreads, so B_lds is free to reuse)
    _Float16* Vl = B_lds;  // [128 cols][pad 40]  (40*2B = 80B, 16B aligned)
#pragma unroll
    for (int t = 0; t < 4; t++)
#pragma unroll
      for (int r = 0; r < 4; r++) {
        int lrow = mw + quad * 4 + r;
        int col = nw + t * 16 + l16;
        Vl[col * 40 + lrow] = (_Float16)acc[t][r];
      }
    __syncthreads();
    int col = tid >> 1, hh = tid & 1;
    int bb = m0 >> 11, s0 = (m0 & 2047) + hh * 16;
    half8 h0 = *(half8*)&Vl[col * 40 + hh * 16];
    half8 h1 = *(half8*)&Vl[col * 40 + hh * 16 + 8];
    _Float16* dstv = Vt + ((size_t)(bb * 128 + col)) * 2048 + s0;
    *(half8*)&dstv[0] = h0;
    *(half8*)&dstv[8] = h1;
  }
}

// ---------------------------------------------------------------------------
// Kernel 3: flash-attention partial, one 256-key chunk per block, processed
// as two 128-key sub-chunks with online softmax (running m,l; O rescaled in
// registers). Exact 576-block 1D grid (4 batches x 144 (qt,kc) pairs) --
// all blocks co-resident at 3 blocks/CU, so no tail wave. Opart halves vs
// the 128-key version (9.2 MB vs 17.8 MB) and combine depth halves (<=8).
// K staged in LDS; V prefetched to REGISTERS during K-phase, then dumped into
// the SAME LDS buffer after softmax. 52.2 KB -> 3 blocks/CU.
// ---------------------------------------------------------------------------
__global__ __launch_bounds__(256, 3) void attn_partial(
    const _Float16* __restrict__ Qh, const _Float16* __restrict__ Kh,
    const _Float16* __restrict__ Vt, _Float16* __restrict__ Opart,
    float* __restrict__ Ml) {
  __shared__ _Float16 KV_lds[128 * 136];  // K (key-major), then V (feat-major)
  __shared__ _Float16 P_lds[4 * 16 * 136];
  int tid = threadIdx.x;
  int w = tid >> 6, lane = tid & 63, quad = lane >> 4, l16 = lane & 15;
  int g = (int)blockIdx.x;
  int b = g & 3;
  int r = g >> 2;  // 0..143: group m has 4 qtiles x (m+1) chunks, offset 2m(m+1)
  int m = (int)sqrtf((float)r * 0.5f);
  while (2 * m * (m + 1) > r) m--;
  while (2 * (m + 1) * (m + 2) <= r) m++;
  int r0_ = r - 2 * m * (m + 1);
  int qdiv = r0_ / (m + 1);
  int qt = 4 * m + qdiv;
  int kc = r0_ - qdiv * (m + 1);
  int q0 = qt * 64, k0 = kc * 256;
  int kmax = (qt + 1) * 64;
  int len = kmax - k0; if (len > 256) len = 256;
  int nsub = (len + 127) >> 7;  // 1 or 2
  int qw0 = q0 + w * 16;
  int sidx = (b * 32 + qt) * 8 + kc;

  const _Float16* Kb = Qh;  // placeholder to keep compiler happy on aliasing
  Kb = Kh + (size_t)b * 2048 * 128;
  const _Float16* Vb = Vt + (size_t)b * 128 * 2048;

  half8 aq[4];
  {
    const _Float16* qbase = Qh + (size_t)(b * 2048 + qw0 + l16) * 128;
#pragma unroll
    for (int c = 0; c < 4; c++) aq[c] = *(const half8*)&qbase[c * 32 + quad * 8];
  }

  int srow = tid >> 1, scol = (tid & 1) * 64;
  floatx4 zero = {0.f, 0.f, 0.f, 0.f};
  floatx4 O[8];
#pragma unroll
  for (int t = 0; t < 8; t++) O[t] = zero;
  float m_r[4] = {MASKVAL, MASKVAL, MASKVAL, MASKVAL};
  float l_r[4] = {0.f, 0.f, 0.f, 0.f};

  for (int s = 0; s < nsub; s++) {
    int ks = k0 + s * 128;
    if (s) __syncthreads();  // prev PV done with KV_lds/P_lds
#pragma unroll
    for (int i = 0; i < 8; i++)
      *(half8*)&KV_lds[srow * 136 + scol + i * 8] =
          *(const half8*)&Kb[(size_t)(ks + srow) * 128 + scol + i * 8];
    half8 vreg[8];
#pragma unroll
    for (int i = 0; i < 8; i++)
      vreg[i] = *(const half8*)&Vb[(size_t)srow * 2048 + ks + scol + i * 8];
    __syncthreads();

    floatx4 sa[8];
#pragma unroll
    for (int t = 0; t < 8; t++) sa[t] = zero;
#pragma unroll
    for (int t = 0; t < 8; t++)
#pragma unroll
      for (int c = 0; c < 4; c++) {
        half8 bk = *(const half8*)&KV_lds[(t * 16 + l16) * 136 + c * 32 + quad * 8];
        sa[t] = MFMA16(aq[c], bk, sa[t]);
      }

    float sc[4];
#pragma unroll
    for (int j = 0; j < 4; j++) {
      int query = qw0 + quad * 4 + j;
      float mx = MASKVAL;
#pragma unroll
      for (int t = 0; t < 8; t++) {
        float v = (ks + t * 16 + l16 > query) ? MASKVAL : sa[t][j];
        sa[t][j] = v;
        mx = fmaxf(mx, v);
      }
#pragma unroll
      for (int off = 1; off < 16; off <<= 1) mx = fmaxf(mx, __shfl_xor(mx, off));
      float mnew = fmaxf(m_r[j], mx);
      float scj = exp2f(m_r[j] - mnew);
      float rs = 0.f;
#pragma unroll
      for (int t = 0; t < 8; t++) {
        float e = exp2f(sa[t][j] - mnew);
        sa[t][j] = e;
        rs += e;
      }
#pragma unroll
      for (int off = 1; off < 16; off <<= 1) rs += __shfl_xor(rs, off);
      l_r[j] = l_r[j] * scj + rs;
      m_r[j] = mnew;
      sc[j] = scj;
    }
    // rescale running O by per-row correction before accumulating this chunk
#pragma unroll
    for (int t = 0; t < 8; t++)
#pragma unroll
      for (int j = 0; j < 4; j++) O[t][j] *= sc[j];

    __syncthreads();  // all waves done reading K from KV_lds
#pragma unroll
    for (int i = 0; i < 8; i++)
      *(half8*)&KV_lds[srow * 136 + scol + i * 8] = vreg[i];
    _Float16* P = P_lds + w * 16 * 136;
#pragma unroll
    for (int j = 0; j < 4; j++)
#pragma unroll
      for (int t = 0; t < 8; t++)
        P[(quad * 4 + j) * 136 + t * 16 + l16] = (_Float16)sa[t][j];
    __syncthreads();  // V,P visible to all waves

#pragma unroll
    for (int c2 = 0; c2 < 4; c2++) {
      half8 ap = *(const half8*)&P[l16 * 136 + c2 * 32 + quad * 8];
#pragma unroll
      for (int t = 0; t < 8; t++) {
        half8 bv = *(const half8*)&KV_lds[(t * 16 + l16) * 136 + c2 * 32 + quad * 8];
        O[t] = MFMA16(ap, bv, O[t]);
      }
    }
  }

  size_t obase = (size_t)sidx * 8192;
#pragma unroll
  for (int t = 0; t < 8; t++)
#pragma unroll
    for (int j = 0; j < 4; j++)
      Opart[obase + (size_t)(w * 16 + quad * 4 + j) * 128 + t * 16 + l16] = (_Float16)O[t][j];
  if (l16 == 0)
#pragma unroll
    for (int j = 0; j < 4; j++) {
      int row = w * 16 + quad * 4 + j;
      floatx2 ml;
      ml[0] = m_r[j];
      ml[1] = l_r[j];
      *(floatx2*)&Ml[(size_t)sidx * 128 + row * 2] = ml;
    }
}

// ---------------------------------------------------------------------------
// Kernel 3b: combine partials (up to 8/row). One wave per query row.
// Fully-unrolled predicated loops so all Ml/Opart loads issue concurrently
// (the previous runtime-bounded loop serialized ~16 dependent loads).
// ---------------------------------------------------------------------------
__global__ __launch_bounds__(256) void attn_combine(
    const _Float16* __restrict__ Opart, const float* __restrict__ Ml,
    _Float16* __restrict__ ctx) {
  int tid = threadIdx.x;
  int w = tid >> 6, lane = tid & 63;
  int row = blockIdx.x * 4 + w;
  int b = row >> 11, s = row & 2047;
  int qt = s >> 6, ri = s & 63;
  int nkc = (qt + 4) >> 2;  // ceil((qt+1)/4)
  int sidx0 = (b * 32 + qt) * 8;
  float mv[8], lv[8];
#pragma unroll
  for (int i = 0; i < 8; i++) {
    if (i < nkc) {
      floatx2 ml = *(const floatx2*)&Ml[(size_t)(sidx0 + i) * 128 + ri * 2];
      mv[i] = ml[0]; lv[i] = ml[1];
    } else { mv[i] = MASKVAL; lv[i] = 0.f; }
  }
  float M = MASKVAL;
#pragma unroll
  for (int i = 0; i < 8; i++) M = fmaxf(M, mv[i]);
  float L = 0.f, a0 = 0.f, a1 = 0.f;
#pragma unroll
  for (int i = 0; i < 8; i++) {
    if (i < nkc) {
      float scv = exp2f(mv[i] - M);
      L += lv[i] * scv;
      half2_t o = *(const half2_t*)&Opart[(size_t)(sidx0 + i) * 8192 + (size_t)ri * 128 + lane * 2];
      a0 += scv * (float)o[0];
      a1 += scv * (float)o[1];
    }
  }
  float inv = 1.f / L;
  half2_t hv;
  hv[0] = (_Float16)(a0 * inv);
  hv[1] = (_Float16)(a1 * inv);
  *(half2_t*)&ctx[(size_t)row * 128 + lane * 2] = hv;
}

// ---------------------------------------------------------------------------
// Kernel 4: out projection ctx[8192,128] x wo[128,1024] -> fp32 out.
// ---------------------------------------------------------------------------
__global__ __launch_bounds__(256) void out_gemm(
    const _Float16* __restrict__ ctx, const _Float16* __restrict__ wot,
    float* __restrict__ out) {
  __shared__ _Float16 A_lds[64 * 136];
  __shared__ _Float16 B_lds[128 * 136];
  int tid = threadIdx.x;
  int w = tid >> 6, lane = tid & 63, quad = lane >> 4, l16 = lane & 15;
  int m0 = blockIdx.x * 64, n0 = blockIdx.y * 128;
  {
    int row = tid >> 2, kk = (tid & 3) * 32;
#pragma unroll
    for (int i = 0; i < 4; i++)
      *(half8*)&A_lds[row * 136 + kk + i * 8] =
          *(const half8*)&ctx[(size_t)(m0 + row) * 128 + kk + i * 8];
  }
  {
    int n = tid >> 1, kk = (tid & 1) * 64;
#pragma unroll
    for (int i = 0; i < 8; i++)
      *(half8*)&B_lds[n * 136 + kk + i * 8] =
          *(const half8*)&wot[(size_t)(n0 + n) * 128 + kk + i * 8];
  }
  __syncthreads();
  floatx4 zero = {0.f, 0.f, 0.f, 0.f};
  floatx4 acc[8];
#pragma unroll
  for (int t = 0; t < 8; t++) acc[t] = zero;
  half8 a[4];
#pragma unroll
  for (int c = 0; c < 4; c++) a[c] = *(const half8*)&A_lds[(w * 16 + l16) * 136 + c * 32 + quad * 8];
#pragma unroll
  for (int t = 0; t < 8; t++)
#pragma unroll
    for (int c = 0; c < 4; c++) {
      half8 b = *(const half8*)&B_lds[(t * 16 + l16) * 136 + c * 32 + quad * 8];
      acc[t] = MFMA16(a[c], b, acc[t]);
    }
#pragma unroll
  for (int t = 0; t < 8; t++)
#pragma unroll
    for (int r = 0; r < 4; r++) {
      int row = m0 + w * 16 + quad * 4 + r;
      out[(size_t)row * 1024 + n0 + t * 16 + l16] = acc[t][r];
    }
}

// ---------------------------------------------------------------------------
extern "C" void kernel_launch(void* const* d_in, const int* in_sizes, int n_in,
                              void* d_out, int out_size, void* d_ws, size_t ws_size,
                              hipStream_t stream) {
  const float* x = (const float*)d_in[0];
  const float* wq = (const float*)d_in[1];
  const float* wk = (const float*)d_in[2];
  const float* wv = (const float*)d_in[3];
  const float* wo = (const float*)d_in[4];
  char* ws = (char*)d_ws;
  _Float16* wqt = (_Float16*)(ws + 0);
  _Float16* wkt = (_Float16*)(ws + 262144);
  _Float16* wvt = (_Float16*)(ws + 524288);
  _Float16* wot = (_Float16*)(ws + 786432);
  _Float16* Qh  = (_Float16*)(ws + 1048576);              // 2 MB
  _Float16* Kh  = (_Float16*)(ws + 3145728);              // 2 MB
  _Float16* Vt  = (_Float16*)(ws + 5242880);              // 2 MB
  _Float16* ctxh = (_Float16*)(ws + 7340032);             // 2 MB
  _Float16* Opart = (_Float16*)(ws + 9437184);            // 1024 x 16 KB = 16 MB
  float* Ml = (float*)(ws + 26214400);                    // 512 KB
  float* out = (float*)d_out;

  wprep<<<512, 256, 0, stream>>>(wq, wk, wv, wo, wqt, wkt, wvt, wot);
  qkv_gemm<<<dim3(256, 3), 256, 0, stream>>>(x, wqt, wkt, wvt, Qh, Kh, Vt);
  attn_partial<<<576, 256, 0, stream>>>(Qh, Kh, Vt, Opart, Ml);
  attn_combine<<<2048, 256, 0, stream>>>(Opart, Ml, ctxh);
  out_gemm<<<dim3(128, 8), 256, 0, stream>>>(ctxh, wot, out);
}